// Round 10
// baseline (225.222 us; speedup 1.0000x reference)
//
#include <hip/hip_runtime.h>
#include <math.h>

#define NN 10000
#define EE 160000
#define DIM 256
#define KK 512            // concatenated K = 2*DIM
#define CAP 64            // bucket capacity = wavefront size: slot list in 1 per-lane load
#define EPS_BN 1e-5f
#define AST 516           // LDS A-tile row stride in shorts (1032 B = 8B-aligned, 2-way banks)

typedef __attribute__((ext_vector_type(8)))  short bf16x8;
typedef __attribute__((ext_vector_type(16))) float f32x16;

union U16 { uint2 u2[2]; bf16x8 v; };

static __device__ __forceinline__ unsigned short f2bf(float f) {
    unsigned u = __float_as_uint(f);
    unsigned r = (u + 0x7fffu + ((u >> 16) & 1u)) >> 16;   // RTNE
    return (unsigned short)r;
}
static __device__ __forceinline__ float bflo(unsigned v) { return __uint_as_float(v << 16); }
static __device__ __forceinline__ float bfhi(unsigned v) { return __uint_as_float(v & 0xffff0000u); }
static __device__ __forceinline__ unsigned packbf(float a, float b) {
    return (unsigned)f2bf(a) | ((unsigned)f2bf(b) << 16);
}

struct Params {
    const float* x; const int* src; const int* dst;
    const float *Ws0, *Wn0, *Ws1, *Wn1, *Ws2, *Wn2;
    const float *g0, *be0, *g1, *be1, *g2, *be2;
    float* out;
    unsigned short* hx;     // [NN][DIM] bf16 x (input of L0)
    unsigned short* z0;     // [NN][DIM] bf16 raw z ping
    unsigned short* z1;     // [NN][DIM] bf16 raw z pong
    unsigned short* magg;   // [NN][DIM] bf16 neighbor-mean of normalized h
    unsigned short* wcat;   // [3][DIM][KK] bf16, [n][k]
    float* stats;           // [3][2*DIM]
    int* cnt;               // [NN]
    int* slots;             // [NN][CAP]
};

static __device__ __forceinline__ void accum8(float* a, uint4 v) {
    a[0] += bflo(v.x); a[1] += bfhi(v.x);
    a[2] += bflo(v.y); a[3] += bfhi(v.y);
    a[4] += bflo(v.z); a[5] += bfhi(v.z);
    a[6] += bflo(v.w); a[7] += bfhi(v.w);
}
static __device__ __forceinline__ void accum8n(float* a, uint4 v,
                                               const float* sc, const float* sh) {
    a[0] += fmaxf(bflo(v.x) * sc[0] + sh[0], 0.f);
    a[1] += fmaxf(bfhi(v.x) * sc[1] + sh[1], 0.f);
    a[2] += fmaxf(bflo(v.y) * sc[2] + sh[2], 0.f);
    a[3] += fmaxf(bfhi(v.y) * sc[3] + sh[3], 0.f);
    a[4] += fmaxf(bflo(v.z) * sc[4] + sh[4], 0.f);
    a[5] += fmaxf(bfhi(v.z) * sc[5] + sh[5], 0.f);
    a[6] += fmaxf(bflo(v.w) * sc[6] + sh[6], 0.f);
    a[7] += fmaxf(bfhi(v.w) * sc[7] + sh[7], 0.f);
}

// ---------------- prep: converts + zeroing ----------------
__global__ __launch_bounds__(256) void k_prep(Params P) {
    int g0 = blockIdx.x * 256 + threadIdx.x;
    int stride = gridDim.x * 256;
    for (int g = g0; g < NN * 64; g += stride) {            // x -> hx bf16 [NN][256]
        int r = g >> 6, c4 = (g & 63) * 4;
        float4 v = *(const float4*)(P.x + (size_t)r * DIM + c4);
        uint2 p; p.x = packbf(v.x, v.y); p.y = packbf(v.z, v.w);
        *(uint2*)(P.hx + (size_t)r * DIM + c4) = p;
    }
    for (int g = g0; g < 3 * DIM * KK; g += stride) {       // [Ws;Wn] -> wcat [n][k]
        int L = g >> 17; int i = g & 131071;
        int k = i >> 8, n = i & 255;
        const float* Ws = (L == 0) ? P.Ws0 : ((L == 1) ? P.Ws1 : P.Ws2);
        const float* Wn = (L == 0) ? P.Wn0 : ((L == 1) ? P.Wn1 : P.Wn2);
        float v = (k < DIM) ? Ws[(size_t)k * DIM + n] : Wn[(size_t)(k - DIM) * DIM + n];
        P.wcat[(size_t)L * DIM * KK + (size_t)n * KK + k] = f2bf(v);
    }
    for (int g = g0; g < NN + 6 * DIM; g += stride) {
        if (g < NN) P.cnt[g] = 0;
        else P.stats[g - NN] = 0.f;
    }
}

// ---------------- bucket build ----------------
__global__ __launch_bounds__(256) void k_bucket(Params P) {
    int e = blockIdx.x * 256 + threadIdx.x;
    if (e < EE) {
        int d = P.dst[e];
        int p = atomicAdd(&P.cnt[d], 1);
        if (p < CAP) P.slots[(size_t)d * CAP + p] = P.src[e];
    }
}

// ---------------- gather: magg[n] = mean over in-neighbors ----------------
// R20: 9-launch pipeline -- k_pre is gone; gather reads RAW z and applies the
// BN+relu affine PER-EDGE inline (R13-proven numerics, absmax 0.0117). Gather
// is L2-request-rate bound at ~15% VALUBusy, so the extra FMAs are free and
// the hn round-trip (~20 MB) disappears. Wave-per-node, no LDS, no barrier;
// 2500 blocks x 256 = 10000 waves. All __shfl in wave-uniform flow (R12
// lesson: ds_bpermute from inactive lanes is undefined).
__global__ __launch_bounds__(256) void k_gather(Params P, int L,
                                                const unsigned short* __restrict__ hsrc,
                                                unsigned short* __restrict__ magg) {
    int t = threadIdx.x;
    int wave = t >> 6, lane = t & 63;
    int h = lane >> 5, l = lane & 31;

    float sc[8], sh[8];
    if (L > 0) {                                            // BN affine of prev layer
        const float* st  = P.stats + (L - 1) * 2 * DIM;
        const float* gam = (L == 1) ? P.g0 : P.g1;
        const float* bet = (L == 1) ? P.be0 : P.be1;
#pragma unroll
        for (int i = 0; i < 8; ++i) {
            int c = l * 8 + i;
            float mu  = st[c] * (1.0f / NN);
            float var = st[DIM + c] * (1.0f / NN) - mu * mu;
            float k = rsqrtf(var + EPS_BN) * gam[c];
            sc[i] = k;
            sh[i] = bet[c] - mu * k;
        }
    }
    int node = blockIdx.x * 4 + wave;                       // exact: 2500*4 = 10000
    if (node >= NN) return;                                 // wave-uniform
    int cnt = P.cnt[node]; if (cnt > CAP) cnt = CAP;
    int sv = P.slots[(size_t)node * CAP + lane];            // slot list in registers
    const uint4* srcm = (const uint4*)hsrc;
    float a[8] = {0, 0, 0, 0, 0, 0, 0, 0};
    int j = 0;                                              // UNIFORM loop var
    for (; j + 15 < cnt; j += 16) {                         // 8 loads in flight/half
        int r0 = __shfl(sv, j +  0 + h), r1 = __shfl(sv, j +  2 + h);
        int r2 = __shfl(sv, j +  4 + h), r3 = __shfl(sv, j +  6 + h);
        int r4 = __shfl(sv, j +  8 + h), r5 = __shfl(sv, j + 10 + h);
        int r6 = __shfl(sv, j + 12 + h), r7 = __shfl(sv, j + 14 + h);
        uint4 v0 = srcm[(size_t)r0 * 32 + l];
        uint4 v1 = srcm[(size_t)r1 * 32 + l];
        uint4 v2 = srcm[(size_t)r2 * 32 + l];
        uint4 v3 = srcm[(size_t)r3 * 32 + l];
        uint4 v4 = srcm[(size_t)r4 * 32 + l];
        uint4 v5 = srcm[(size_t)r5 * 32 + l];
        uint4 v6 = srcm[(size_t)r6 * 32 + l];
        uint4 v7 = srcm[(size_t)r7 * 32 + l];
        if (L == 0) {
            accum8(a, v0); accum8(a, v1); accum8(a, v2); accum8(a, v3);
            accum8(a, v4); accum8(a, v5); accum8(a, v6); accum8(a, v7);
        } else {
            accum8n(a, v0, sc, sh); accum8n(a, v1, sc, sh);
            accum8n(a, v2, sc, sh); accum8n(a, v3, sc, sh);
            accum8n(a, v4, sc, sh); accum8n(a, v5, sc, sh);
            accum8n(a, v6, sc, sh); accum8n(a, v7, sc, sh);
        }
    }
    for (; j + 3 < cnt; j += 4) {
        int r0 = __shfl(sv, j + h), r1 = __shfl(sv, j + 2 + h);
        uint4 v0 = srcm[(size_t)r0 * 32 + l];
        uint4 v1 = srcm[(size_t)r1 * 32 + l];
        if (L == 0) { accum8(a, v0); accum8(a, v1); }
        else { accum8n(a, v0, sc, sh); accum8n(a, v1, sc, sh); }
    }
    for (; j + 1 < cnt; j += 2) {
        int r0 = __shfl(sv, j + h);
        uint4 v0 = srcm[(size_t)r0 * 32 + l];
        if (L == 0) accum8(a, v0); else accum8n(a, v0, sc, sh);
    }
    if (j < cnt) {                                          // odd leftover, uniform shfl
        int r0 = __shfl(sv, cnt - 1);
        uint4 v0 = srcm[(size_t)r0 * 32 + l];
        if (h == 0) {
            if (L == 0) accum8(a, v0); else accum8n(a, v0, sc, sh);
        }
    }
#pragma unroll
    for (int q = 0; q < 8; ++q) a[q] += __shfl_xor(a[q], 32);
    if (h == 0) {
        float inv = 1.0f / (float)(cnt > 1 ? cnt : 1);
        uint4 o;
        o.x = packbf(a[0] * inv, a[1] * inv);
        o.y = packbf(a[2] * inv, a[3] * inv);
        o.z = packbf(a[4] * inv, a[5] * inv);
        o.w = packbf(a[6] * inv, a[7] * inv);
        ((uint4*)magg)[(size_t)node * 32 + l] = o;
    }
}

// ---------------- dense GEMM + stats: z' = [relu(bn(z)) | magg] @ wcat ----
// grid 313 x 512 (8 waves), 32 rows/block. Own-row normalized INLINE during
// staging (R18-proven code); magg staged raw. LDS stores are uint2 (8B): At
// row stride 1032 B is only 8B-aligned. Phase B: wave w = cols w*32..w*32+31,
// one 32x32x16 MFMA chain over KK=512.
__global__ __launch_bounds__(512) void k_gemm(Params P, int L,
                                              const unsigned short* __restrict__ hsrc,
                                              const unsigned short* __restrict__ magg,
                                              unsigned short* __restrict__ gdst) {
    __shared__ unsigned short At[32][AST];                  // 33 KB
    int t = threadIdx.x;
    int wave = t >> 6, lane = t & 63;
    int h = lane >> 5, l = lane & 31;

    // ---- stage A-tile: thread = (row-slot rs, 8-col group cgS), 2 rows ----
    {
        int cgS = t & 31, rs = t >> 5;
        float scg[8], shg[8];
        if (L > 0) {
            const float* stp = P.stats + (L - 1) * 2 * DIM;
            const float* gam = (L == 1) ? P.g0 : P.g1;
            const float* bet = (L == 1) ? P.be0 : P.be1;
#pragma unroll
            for (int i = 0; i < 8; ++i) {
                int c = cgS * 8 + i;
                float mu  = stp[c] * (1.0f / NN);
                float var = stp[DIM + c] * (1.0f / NN) - mu * mu;
                float k = rsqrtf(var + EPS_BN) * gam[c];
                scg[i] = k;
                shg[i] = bet[c] - mu * k;
            }
        }
#pragma unroll
        for (int rr = 0; rr < 2; ++rr) {
            int r = rs + rr * 16;
            int node = blockIdx.x * 32 + r;
            unsigned short* arow = &At[r][0];
            if (node < NN) {
                uint4 ov = *(const uint4*)(hsrc + (size_t)node * DIM + cgS * 8);
                if (L > 0) {
                    uint4 o;
                    o.x = packbf(fmaxf(bflo(ov.x) * scg[0] + shg[0], 0.f),
                                 fmaxf(bfhi(ov.x) * scg[1] + shg[1], 0.f));
                    o.y = packbf(fmaxf(bflo(ov.y) * scg[2] + shg[2], 0.f),
                                 fmaxf(bfhi(ov.y) * scg[3] + shg[3], 0.f));
                    o.z = packbf(fmaxf(bflo(ov.z) * scg[4] + shg[4], 0.f),
                                 fmaxf(bfhi(ov.z) * scg[5] + shg[5], 0.f));
                    o.w = packbf(fmaxf(bflo(ov.w) * scg[6] + shg[6], 0.f),
                                 fmaxf(bfhi(ov.w) * scg[7] + shg[7], 0.f));
                    ov = o;
                }
                *(uint2*)(arow + cgS * 8)     = make_uint2(ov.x, ov.y);
                *(uint2*)(arow + cgS * 8 + 4) = make_uint2(ov.z, ov.w);
                uint4 mv = *(const uint4*)(magg + (size_t)node * DIM + cgS * 8);
                *(uint2*)(arow + 256 + cgS * 8)     = make_uint2(mv.x, mv.y);
                *(uint2*)(arow + 256 + cgS * 8 + 4) = make_uint2(mv.z, mv.w);
            } else {
                uint2 z2 = make_uint2(0u, 0u);
                *(uint2*)(arow + cgS * 8)           = z2;
                *(uint2*)(arow + cgS * 8 + 4)       = z2;
                *(uint2*)(arow + 256 + cgS * 8)     = z2;
                *(uint2*)(arow + 256 + cgS * 8 + 4) = z2;
            }
        }
    }
    __syncthreads();

    // ---- phase B: one 32x32x16 MFMA chain per wave ----
    const unsigned short* wcatL = P.wcat + (size_t)L * DIM * KK;
    float* statsL = P.stats + L * 2 * DIM;
    int m = l;
    int row0 = blockIdx.x * 32;
    int colw0 = wave * 32;                                  // 8 waves x 32 = 256 cols
    const unsigned short* Bp = wcatL + (size_t)(colw0 + m) * KK + h * 8;
    const unsigned short* Arow = &At[m][0];
    f32x16 acc;
#pragma unroll
    for (int i = 0; i < 16; ++i) acc[i] = 0.f;
#pragma unroll 8
    for (int k0 = 0; k0 < KK; k0 += 16) {
        U16 ua;
        ua.u2[0] = *(const uint2*)(Arow + k0 + h * 8);
        ua.u2[1] = *(const uint2*)(Arow + k0 + h * 8 + 4);
        bf16x8 av = ua.v;
        bf16x8 bv = *(const bf16x8*)(Bp + k0);
        acc = __builtin_amdgcn_mfma_f32_32x32x16_bf16(av, bv, acc, 0, 0, 0);
    }
    int cc = colw0 + m;
    float s = 0.f, s2 = 0.f;
#pragma unroll
    for (int reg = 0; reg < 16; ++reg) {
        int r = row0 + (reg & 3) + 8 * (reg >> 2) + 4 * h;
        if (r < NN) {
            float v = acc[reg];
            gdst[(size_t)r * DIM + cc] = f2bf(v);
            s += v; s2 += v * v;
        }
    }
    s  += __shfl_down(s, 32);
    s2 += __shfl_down(s2, 32);
    if (h == 0) {
        atomicAdd(&statsL[cc], s);
        atomicAdd(&statsL[DIM + cc], s2);
    }
}

// ---------------- final BN + sigmoid -> out (fp32) ----------------
__global__ __launch_bounds__(256) void k_norm(Params P) {
    const float* statsL = P.stats + 2 * 2 * DIM;
    int t = threadIdx.x;
    int c8 = (t & 31) * 8;
    int r = blockIdx.x * 8 + (t >> 5);                      // grid 1250
    float sc[8], sh[8];
#pragma unroll
    for (int i = 0; i < 8; ++i) {
        int c = c8 + i;
        float mu  = statsL[c] * (1.0f / NN);
        float var = statsL[DIM + c] * (1.0f / NN) - mu * mu;
        float k = rsqrtf(var + EPS_BN) * P.g2[c];
        sc[i] = k;
        sh[i] = P.be2[c] - mu * k;
    }
    uint4 v = *(const uint4*)(P.z0 + (size_t)r * DIM + c8);
    float f[8] = {bflo(v.x), bfhi(v.x), bflo(v.y), bfhi(v.y),
                  bflo(v.z), bfhi(v.z), bflo(v.w), bfhi(v.w)};
#pragma unroll
    for (int i = 0; i < 8; ++i) f[i] = f[i] * sc[i] + sh[i];
    float4 o0, o1;
    o0.x = 1.0f / (1.0f + __expf(-f[0]));
    o0.y = 1.0f / (1.0f + __expf(-f[1]));
    o0.z = 1.0f / (1.0f + __expf(-f[2]));
    o0.w = 1.0f / (1.0f + __expf(-f[3]));
    o1.x = 1.0f / (1.0f + __expf(-f[4]));
    o1.y = 1.0f / (1.0f + __expf(-f[5]));
    o1.z = 1.0f / (1.0f + __expf(-f[6]));
    o1.w = 1.0f / (1.0f + __expf(-f[7]));
    *(float4*)(P.out + (size_t)r * DIM + c8)     = o0;
    *(float4*)(P.out + (size_t)r * DIM + c8 + 4) = o1;
}

extern "C" void kernel_launch(void* const* d_in, const int* in_sizes, int n_in,
                              void* d_out, int out_size, void* d_ws, size_t ws_size,
                              hipStream_t stream) {
    Params P;
    P.x   = (const float*)d_in[0];
    P.src = (const int*)d_in[1];
    P.dst = (const int*)d_in[2];
    P.Ws0 = (const float*)d_in[3];  P.Wn0 = (const float*)d_in[4];
    P.g0  = (const float*)d_in[6];  P.be0 = (const float*)d_in[7];
    P.Ws1 = (const float*)d_in[8];  P.Wn1 = (const float*)d_in[9];
    P.g1  = (const float*)d_in[11]; P.be1 = (const float*)d_in[12];
    P.Ws2 = (const float*)d_in[13]; P.Wn2 = (const float*)d_in[14];
    P.g2  = (const float*)d_in[16]; P.be2 = (const float*)d_in[17];
    P.out = (float*)d_out;

    char* ws = (char*)d_ws;
    size_t off = 0;
    P.hx   = (unsigned short*)(ws + off); off += (size_t)NN * DIM * 2;       // 5.12 MB
    P.z0   = (unsigned short*)(ws + off); off += (size_t)NN * DIM * 2;       // 5.12 MB
    P.z1   = (unsigned short*)(ws + off); off += (size_t)NN * DIM * 2;       // 5.12 MB
    P.magg = (unsigned short*)(ws + off); off += (size_t)NN * DIM * 2;       // 5.12 MB
    P.wcat = (unsigned short*)(ws + off); off += (size_t)3 * DIM * KK * 2;   // 0.79 MB
    P.stats = (float*)(ws + off); off += 3 * 2 * DIM * sizeof(float);
    P.cnt   = (int*)(ws + off); off += (size_t)NN * 4; off = (off + 255) & ~(size_t)255;
    P.slots = (int*)(ws + off); off += (size_t)NN * CAP * 4;                 // 2.56 MB
    (void)ws_size;

    // 9-launch pipeline (R20): prep | bucket | 3x(gather | gemm) | norm.
    // k_pre eliminated: gather normalizes per-edge, gemm normalizes own-row
    // inline. Ping-pong: L0 hx->z0, L1 z0->z1, L2 z1->z0; norm reads z0.
    k_prep<<<512, 256, 0, stream>>>(P);
    k_bucket<<<(EE + 255) / 256, 256, 0, stream>>>(P);
    k_gather<<<2500, 256, 0, stream>>>(P, 0, P.hx, P.magg);
    k_gemm<<<313, 512, 0, stream>>>(P, 0, P.hx, P.magg, P.z0);
    k_gather<<<2500, 256, 0, stream>>>(P, 1, P.z0, P.magg);
    k_gemm<<<313, 512, 0, stream>>>(P, 1, P.z0, P.magg, P.z1);
    k_gather<<<2500, 256, 0, stream>>>(P, 2, P.z1, P.magg);
    k_gemm<<<313, 512, 0, stream>>>(P, 2, P.z1, P.magg, P.z0);
    k_norm<<<NN / 8, 256, 0, stream>>>(P);
}

// Round 11
// 219.974 us; speedup vs baseline: 1.0239x; 1.0239x over previous
//
#include <hip/hip_runtime.h>
#include <math.h>

#define NN 10000
#define EE 160000
#define DIM 256
#define KK 512            // concatenated K = 2*DIM
#define CAP 64            // bucket capacity = wavefront size: slot list in 1 per-lane load
#define EPS_BN 1e-5f
#define AST 516           // LDS A-tile row stride in shorts (1032 B = 8B-aligned, 2-way banks)

typedef __attribute__((ext_vector_type(8)))  short bf16x8;
typedef __attribute__((ext_vector_type(16))) float f32x16;

union U16 { uint2 u2[2]; bf16x8 v; };

static __device__ __forceinline__ unsigned short f2bf(float f) {
    unsigned u = __float_as_uint(f);
    unsigned r = (u + 0x7fffu + ((u >> 16) & 1u)) >> 16;   // RTNE
    return (unsigned short)r;
}
static __device__ __forceinline__ float bflo(unsigned v) { return __uint_as_float(v << 16); }
static __device__ __forceinline__ float bfhi(unsigned v) { return __uint_as_float(v & 0xffff0000u); }
static __device__ __forceinline__ unsigned packbf(float a, float b) {
    return (unsigned)f2bf(a) | ((unsigned)f2bf(b) << 16);
}

struct Params {
    const float* x; const int* src; const int* dst;
    const float *Ws0, *Wn0, *Ws1, *Wn1, *Ws2, *Wn2;
    const float *g0, *be0, *g1, *be1, *g2, *be2;
    float* out;
    unsigned short* hx;     // [NN][DIM] bf16 x (input of L0)
    unsigned short* z0;     // [NN][DIM] bf16 raw z ping
    unsigned short* z1;     // [NN][DIM] bf16 raw z pong
    unsigned short* hn;     // [NN][DIM] bf16 pre-normalized h (relu(bn(z)))
    unsigned short* magg;   // [NN][DIM] bf16 neighbor-mean of normalized h
    unsigned short* wcat;   // [3][DIM][KK] bf16, [n][k]
    float* stats;           // [3][2*DIM]   (adjacent to cnt: one memset covers both)
    int* cnt;               // [NN]
    int* slots;             // [NN][CAP]
};

static __device__ __forceinline__ void accum8(float* a, uint4 v) {
    a[0] += bflo(v.x); a[1] += bfhi(v.x);
    a[2] += bflo(v.y); a[3] += bfhi(v.y);
    a[4] += bflo(v.z); a[5] += bfhi(v.z);
    a[6] += bflo(v.w); a[7] += bfhi(v.w);
}

// ---------------- prep + bucket (fused; cnt/stats zeroed by memset) -------
// cnt is zeroed by the hipMemsetAsync issued before this kernel on the same
// stream, so the bucket atomics here are safe from block 0 onward.
__global__ __launch_bounds__(256) void k_prep(Params P) {
    int g0 = blockIdx.x * 256 + threadIdx.x;
    int stride = gridDim.x * 256;
    for (int g = g0; g < NN * 32; g += stride) {            // x -> hx bf16, 8-wide
        int r = g >> 5, c8 = (g & 31) * 8;
        const float4* xp = (const float4*)(P.x + (size_t)r * DIM + c8);
        float4 v0 = xp[0], v1 = xp[1];
        uint4 p;
        p.x = packbf(v0.x, v0.y); p.y = packbf(v0.z, v0.w);
        p.z = packbf(v1.x, v1.y); p.w = packbf(v1.z, v1.w);
        *(uint4*)(P.hx + (size_t)r * DIM + c8) = p;
    }
    for (int g = g0; g < 3 * DIM * KK; g += stride) {       // [Ws;Wn] -> wcat [n][k]
        int L = g >> 17; int i = g & 131071;
        int k = i >> 8, n = i & 255;
        const float* Ws = (L == 0) ? P.Ws0 : ((L == 1) ? P.Ws1 : P.Ws2);
        const float* Wn = (L == 0) ? P.Wn0 : ((L == 1) ? P.Wn1 : P.Wn2);
        float v = (k < DIM) ? Ws[(size_t)k * DIM + n] : Wn[(size_t)(k - DIM) * DIM + n];
        P.wcat[(size_t)L * DIM * KK + (size_t)n * KK + k] = f2bf(v);
    }
    for (int e = g0; e < EE; e += stride) {                 // bucket build
        int d = P.dst[e];
        int p = atomicAdd(&P.cnt[d], 1);
        if (p < CAP) P.slots[(size_t)d * CAP + p] = P.src[e];
    }
}

// ---------------- pre-normalize: hn = relu(bn_affine(z)) ----------------
// Per-NODE (10k rows) instead of per-EDGE -- 16x less VALU (R15-proven).
// grid 1250 x 256: 8 rows/block, 32 threads/row, 8 bf16/thread.
__global__ __launch_bounds__(256) void k_pre(Params P, int Lprev,
                                             const unsigned short* __restrict__ z,
                                             unsigned short* __restrict__ hn) {
    const float* st  = P.stats + Lprev * 2 * DIM;
    const float* gam = (Lprev == 0) ? P.g0 : P.g1;
    const float* bet = (Lprev == 0) ? P.be0 : P.be1;
    int t = threadIdx.x;
    int c8 = (t & 31) * 8;
    int r = blockIdx.x * 8 + (t >> 5);
    float sc[8], sh[8];
#pragma unroll
    for (int i = 0; i < 8; ++i) {
        int c = c8 + i;
        float mu  = st[c] * (1.0f / NN);
        float var = st[DIM + c] * (1.0f / NN) - mu * mu;
        float k = rsqrtf(var + EPS_BN) * gam[c];
        sc[i] = k;
        sh[i] = bet[c] - mu * k;
    }
    uint4 v = *(const uint4*)(z + (size_t)r * DIM + c8);
    uint4 o;
    o.x = packbf(fmaxf(bflo(v.x) * sc[0] + sh[0], 0.f),
                 fmaxf(bfhi(v.x) * sc[1] + sh[1], 0.f));
    o.y = packbf(fmaxf(bflo(v.y) * sc[2] + sh[2], 0.f),
                 fmaxf(bfhi(v.y) * sc[3] + sh[3], 0.f));
    o.z = packbf(fmaxf(bflo(v.z) * sc[4] + sh[4], 0.f),
                 fmaxf(bfhi(v.z) * sc[5] + sh[5], 0.f));
    o.w = packbf(fmaxf(bflo(v.w) * sc[6] + sh[6], 0.f),
                 fmaxf(bfhi(v.w) * sc[7] + sh[7], 0.f));
    *(uint4*)(hn + (size_t)r * DIM + c8) = o;
}

// ---------------- gather: magg[n] = mean over in-neighbors of hsrc -------
// R15-proven (best measured config). Wave-per-node, NO LDS, NO barrier:
// 2500 blocks x 256 (4 waves) = 10000 waves; waves retire independently.
// Half-waves split edges; all __shfl in wave-uniform flow (R12 lesson:
// ds_bpermute from inactive lanes is undefined).
__global__ __launch_bounds__(256) void k_gather(Params P,
                                                const unsigned short* __restrict__ hsrc,
                                                unsigned short* __restrict__ magg) {
    int t = threadIdx.x;
    int wave = t >> 6, lane = t & 63;
    int h = lane >> 5, l = lane & 31;
    int node = blockIdx.x * 4 + wave;                       // exact: 2500*4 = 10000
    if (node >= NN) return;                                 // wave-uniform
    int cnt = P.cnt[node]; if (cnt > CAP) cnt = CAP;
    int sv = P.slots[(size_t)node * CAP + lane];            // slot list in registers
    const uint4* srcm = (const uint4*)hsrc;
    float a[8] = {0, 0, 0, 0, 0, 0, 0, 0};
    int j = 0;                                              // UNIFORM loop var
    for (; j + 15 < cnt; j += 16) {                         // 8 loads in flight/half
        int r0 = __shfl(sv, j +  0 + h), r1 = __shfl(sv, j +  2 + h);
        int r2 = __shfl(sv, j +  4 + h), r3 = __shfl(sv, j +  6 + h);
        int r4 = __shfl(sv, j +  8 + h), r5 = __shfl(sv, j + 10 + h);
        int r6 = __shfl(sv, j + 12 + h), r7 = __shfl(sv, j + 14 + h);
        uint4 v0 = srcm[(size_t)r0 * 32 + l];
        uint4 v1 = srcm[(size_t)r1 * 32 + l];
        uint4 v2 = srcm[(size_t)r2 * 32 + l];
        uint4 v3 = srcm[(size_t)r3 * 32 + l];
        uint4 v4 = srcm[(size_t)r4 * 32 + l];
        uint4 v5 = srcm[(size_t)r5 * 32 + l];
        uint4 v6 = srcm[(size_t)r6 * 32 + l];
        uint4 v7 = srcm[(size_t)r7 * 32 + l];
        accum8(a, v0); accum8(a, v1); accum8(a, v2); accum8(a, v3);
        accum8(a, v4); accum8(a, v5); accum8(a, v6); accum8(a, v7);
    }
    for (; j + 3 < cnt; j += 4) {
        int r0 = __shfl(sv, j + h), r1 = __shfl(sv, j + 2 + h);
        uint4 v0 = srcm[(size_t)r0 * 32 + l];
        uint4 v1 = srcm[(size_t)r1 * 32 + l];
        accum8(a, v0); accum8(a, v1);
    }
    for (; j + 1 < cnt; j += 2) {
        int r0 = __shfl(sv, j + h);
        uint4 v0 = srcm[(size_t)r0 * 32 + l];
        accum8(a, v0);
    }
    if (j < cnt) {                                          // odd leftover, uniform shfl
        int r0 = __shfl(sv, cnt - 1);
        uint4 v0 = srcm[(size_t)r0 * 32 + l];
        if (h == 0) accum8(a, v0);
    }
#pragma unroll
    for (int q = 0; q < 8; ++q) a[q] += __shfl_xor(a[q], 32);
    if (h == 0) {
        float inv = 1.0f / (float)(cnt > 1 ? cnt : 1);
        uint4 o;
        o.x = packbf(a[0] * inv, a[1] * inv);
        o.y = packbf(a[2] * inv, a[3] * inv);
        o.z = packbf(a[4] * inv, a[5] * inv);
        o.w = packbf(a[6] * inv, a[7] * inv);
        ((uint4*)magg)[(size_t)node * 32 + l] = o;
    }
}

// ---------------- dense GEMM + stats: z' = [hn | magg] @ wcat ------------
// R15-proven. grid 313 x 512 (8 waves), 32 rows/block. Staging is two DENSE
// coalesced streams. LDS stores are uint2 (8B): At row stride 1032 B is only
// 8B-aligned, so b128 LDS writes on odd rows would be misaligned.
// Phase B: wave w = cols w*32..w*32+31, one 32x32x16 MFMA chain over KK=512.
__global__ __launch_bounds__(512) void k_gemm(Params P, int L,
                                              const unsigned short* __restrict__ hsrc,
                                              const unsigned short* __restrict__ magg,
                                              unsigned short* __restrict__ gdst) {
    __shared__ unsigned short At[32][AST];                  // 33 KB
    int t = threadIdx.x;
    int wave = t >> 6, lane = t & 63;
    int h = lane >> 5, l = lane & 31;

    // ---- stage A-tile: row r = t>>4; 16 threads/row, 32 shorts each ----
    {
        int r = t >> 4, q = t & 15;
        int node = blockIdx.x * 32 + r;
        const unsigned short* srcp = (q < 8) ? hsrc : magg;
        int c0 = (q & 7) * 32;                              // 32 shorts = 4 uint4
        unsigned short* dstp = &At[r][(q < 8 ? 0 : 256) + c0];
        if (node < NN) {
            const uint4* gp = (const uint4*)(srcp + (size_t)node * DIM + c0);
            uint4 v0 = gp[0], v1 = gp[1], v2 = gp[2], v3 = gp[3];
            *(uint2*)(dstp)      = make_uint2(v0.x, v0.y);
            *(uint2*)(dstp + 4)  = make_uint2(v0.z, v0.w);
            *(uint2*)(dstp + 8)  = make_uint2(v1.x, v1.y);
            *(uint2*)(dstp + 12) = make_uint2(v1.z, v1.w);
            *(uint2*)(dstp + 16) = make_uint2(v2.x, v2.y);
            *(uint2*)(dstp + 20) = make_uint2(v2.z, v2.w);
            *(uint2*)(dstp + 24) = make_uint2(v3.x, v3.y);
            *(uint2*)(dstp + 28) = make_uint2(v3.z, v3.w);
        } else {
            uint2 z = make_uint2(0u, 0u);
#pragma unroll
            for (int q8 = 0; q8 < 8; ++q8) *(uint2*)(dstp + q8 * 4) = z;
        }
    }
    __syncthreads();

    // ---- phase B: one 32x32x16 MFMA chain per wave ----
    const unsigned short* wcatL = P.wcat + (size_t)L * DIM * KK;
    float* statsL = P.stats + L * 2 * DIM;
    int m = l;
    int row0 = blockIdx.x * 32;
    int colw0 = wave * 32;                                  // 8 waves x 32 = 256 cols
    const unsigned short* Bp = wcatL + (size_t)(colw0 + m) * KK + h * 8;
    const unsigned short* Arow = &At[m][0];
    f32x16 acc;
#pragma unroll
    for (int i = 0; i < 16; ++i) acc[i] = 0.f;
#pragma unroll 8
    for (int k0 = 0; k0 < KK; k0 += 16) {
        U16 ua;
        ua.u2[0] = *(const uint2*)(Arow + k0 + h * 8);
        ua.u2[1] = *(const uint2*)(Arow + k0 + h * 8 + 4);
        bf16x8 av = ua.v;
        bf16x8 bv = *(const bf16x8*)(Bp + k0);
        acc = __builtin_amdgcn_mfma_f32_32x32x16_bf16(av, bv, acc, 0, 0, 0);
    }
    int cc = colw0 + m;
    float s = 0.f, s2 = 0.f;
#pragma unroll
    for (int reg = 0; reg < 16; ++reg) {
        int r = row0 + (reg & 3) + 8 * (reg >> 2) + 4 * h;
        if (r < NN) {
            float v = acc[reg];
            gdst[(size_t)r * DIM + cc] = f2bf(v);
            s += v; s2 += v * v;
        }
    }
    s  += __shfl_down(s, 32);
    s2 += __shfl_down(s2, 32);
    if (h == 0) {
        atomicAdd(&statsL[cc], s);
        atomicAdd(&statsL[DIM + cc], s2);
    }
}

// ---------------- final BN + sigmoid -> out (fp32) ----------------
__global__ __launch_bounds__(256) void k_norm(Params P) {
    const float* statsL = P.stats + 2 * 2 * DIM;
    int t = threadIdx.x;
    int c8 = (t & 31) * 8;
    int r = blockIdx.x * 8 + (t >> 5);                      // grid 1250
    float sc[8], sh[8];
#pragma unroll
    for (int i = 0; i < 8; ++i) {
        int c = c8 + i;
        float mu  = statsL[c] * (1.0f / NN);
        float var = statsL[DIM + c] * (1.0f / NN) - mu * mu;
        float k = rsqrtf(var + EPS_BN) * P.g2[c];
        sc[i] = k;
        sh[i] = P.be2[c] - mu * k;
    }
    uint4 v = *(const uint4*)(P.z0 + (size_t)r * DIM + c8);
    float f[8] = {bflo(v.x), bfhi(v.x), bflo(v.y), bfhi(v.y),
                  bflo(v.z), bfhi(v.z), bflo(v.w), bfhi(v.w)};
#pragma unroll
    for (int i = 0; i < 8; ++i) f[i] = f[i] * sc[i] + sh[i];
    float4 o0, o1;
    o0.x = 1.0f / (1.0f + __expf(-f[0]));
    o0.y = 1.0f / (1.0f + __expf(-f[1]));
    o0.z = 1.0f / (1.0f + __expf(-f[2]));
    o0.w = 1.0f / (1.0f + __expf(-f[3]));
    o1.x = 1.0f / (1.0f + __expf(-f[4]));
    o1.y = 1.0f / (1.0f + __expf(-f[5]));
    o1.z = 1.0f / (1.0f + __expf(-f[6]));
    o1.w = 1.0f / (1.0f + __expf(-f[7]));
    *(float4*)(P.out + (size_t)r * DIM + c8)     = o0;
    *(float4*)(P.out + (size_t)r * DIM + c8 + 4) = o1;
}

extern "C" void kernel_launch(void* const* d_in, const int* in_sizes, int n_in,
                              void* d_out, int out_size, void* d_ws, size_t ws_size,
                              hipStream_t stream) {
    Params P;
    P.x   = (const float*)d_in[0];
    P.src = (const int*)d_in[1];
    P.dst = (const int*)d_in[2];
    P.Ws0 = (const float*)d_in[3];  P.Wn0 = (const float*)d_in[4];
    P.g0  = (const float*)d_in[6];  P.be0 = (const float*)d_in[7];
    P.Ws1 = (const float*)d_in[8];  P.Wn1 = (const float*)d_in[9];
    P.g1  = (const float*)d_in[11]; P.be1 = (const float*)d_in[12];
    P.Ws2 = (const float*)d_in[13]; P.Wn2 = (const float*)d_in[14];
    P.g2  = (const float*)d_in[16]; P.be2 = (const float*)d_in[17];
    P.out = (float*)d_out;

    char* ws = (char*)d_ws;
    size_t off = 0;
    P.hx   = (unsigned short*)(ws + off); off += (size_t)NN * DIM * 2;       // 5.12 MB
    P.z0   = (unsigned short*)(ws + off); off += (size_t)NN * DIM * 2;       // 5.12 MB
    P.z1   = (unsigned short*)(ws + off); off += (size_t)NN * DIM * 2;       // 5.12 MB
    P.hn   = (unsigned short*)(ws + off); off += (size_t)NN * DIM * 2;       // 5.12 MB
    P.magg = (unsigned short*)(ws + off); off += (size_t)NN * DIM * 2;       // 5.12 MB
    P.wcat = (unsigned short*)(ws + off); off += (size_t)3 * DIM * KK * 2;   // 0.79 MB
    // stats + cnt adjacent: one 46144-byte memset zeroes both
    char* zbase = ws + off;
    P.stats = (float*)(ws + off); off += 3 * 2 * DIM * sizeof(float);        // 6144 B
    P.cnt   = (int*)(ws + off); off += (size_t)NN * 4;                       // 40000 B
    size_t znb = (size_t)(ws + off - zbase);
    off = (off + 255) & ~(size_t)255;
    P.slots = (int*)(ws + off); off += (size_t)NN * CAP * 4;                 // 2.56 MB
    (void)ws_size;

    // 10-dispatch pipeline (R21 = R15 best-known + fused prep/bucket):
    // memset | prep+bucket | 3x(gather | gemm) + 2x pre | norm.
    hipMemsetAsync(zbase, 0, znb, stream);
    k_prep<<<512, 256, 0, stream>>>(P);
    // L0: input hx (no BN before layer 0)
    k_gather<<<2500, 256, 0, stream>>>(P, P.hx, P.magg);
    k_gemm<<<313, 512, 0, stream>>>(P, 0, P.hx, P.magg, P.z0);
    // L1
    k_pre<<<1250, 256, 0, stream>>>(P, 0, P.z0, P.hn);
    k_gather<<<2500, 256, 0, stream>>>(P, P.hn, P.magg);
    k_gemm<<<313, 512, 0, stream>>>(P, 1, P.hn, P.magg, P.z1);
    // L2
    k_pre<<<1250, 256, 0, stream>>>(P, 1, P.z1, P.hn);
    k_gather<<<2500, 256, 0, stream>>>(P, P.hn, P.magg);
    k_gemm<<<313, 512, 0, stream>>>(P, 2, P.hn, P.magg, P.z0);
    k_norm<<<NN / 8, 256, 0, stream>>>(P);
}